// Round 15
// baseline (66.776 us; speedup 1.0000x reference)
//
#include <hip/hip_runtime.h>
#include <hip/hip_bf16.h>
#include <stdint.h>

#define SEQ 4096
#define DM 512
#define NH 8
#define HD 64
#define WIN 65

typedef __attribute__((ext_vector_type(8))) short bf16x8;
typedef __attribute__((ext_vector_type(4))) float f32x4;
typedef __attribute__((ext_vector_type(16))) float f32x16;

#define GLOAD_LDS16(gp, lp)                                                 \
  __builtin_amdgcn_global_load_lds(                                         \
      (const __attribute__((address_space(1))) void*)(gp),                  \
      (__attribute__((address_space(3))) void*)(lp), 16, 0, 0)

__device__ __forceinline__ unsigned short f2bf(float f) {
  unsigned int u = __float_as_uint(f);
  u += 0x7FFFu + ((u >> 16) & 1u);
  return (unsigned short)(u >> 16);
}

// ---- fused prep: convert x (f32->bf16) and transpose+convert all 4 W ----
__global__ __launch_bounds__(256) void prep_kernel(
    const float* __restrict__ x, unsigned short* __restrict__ xb,
    const float* __restrict__ w0, const float* __restrict__ w1,
    const float* __restrict__ w2, const float* __restrict__ w3,
    unsigned short* __restrict__ wt) {
  __shared__ float tl[64][65];
  const int bid = blockIdx.x;
  const int t = threadIdx.x;
  if (bid < 4096) {
    const int i = bid * 256 + t;
    float4 v = ((const float4*)x)[i];
    ushort4 o;
    o.x = f2bf(v.x); o.y = f2bf(v.y); o.z = f2bf(v.z); o.w = f2bf(v.w);
    ((ushort4*)xb)[i] = o;
    return;
  }
  const int wtid = bid - 4096;          // [0,256)
  const int z = wtid >> 6;
  const int rem = wtid & 63;
  const int k0 = (rem >> 3) * 64;
  const int n0 = (rem & 7) * 64;
  const float* W = (z == 0) ? w0 : (z == 1) ? w1 : (z == 2) ? w2 : w3;
  unsigned short* o = wt + (size_t)z * 262144;
#pragma unroll
  for (int i = 0; i < 16; ++i) {
    int idx = t + i * 256;
    int r = idx >> 6, c = idx & 63;
    tl[c][r] = W[(size_t)(k0 + r) * 512 + n0 + c];
  }
  __syncthreads();
#pragma unroll
  for (int i = 0; i < 16; ++i) {
    int idx = t + i * 256;
    int r = idx >> 6, c = idx & 63;
    o[(size_t)(n0 + r) * 512 + k0 + c] = f2bf(tl[r][c]);
  }
}

// ---- z-merged QKV GEMM (unchanged from R14): A staged once per K-step ----
__global__ __launch_bounds__(256) void gemm_qkv_kernel(
    const unsigned short* __restrict__ A,
    const unsigned short* __restrict__ wt,
    const float* __restrict__ bq, const float* __restrict__ bk, const float* __restrict__ bv,
    unsigned short* __restrict__ qkv) {
  const int bid = blockIdx.x;
  const int bm = bid & 63;
  const int bn = bid >> 6;            // head 0..7
  const int bm0 = bm * 128;
  const int bn0 = bn * 64;

  __shared__ __align__(16) unsigned char sm[40960];
  unsigned short* As0 = (unsigned short*)sm;                 // [128][32]
  unsigned short* As1 = (unsigned short*)(sm + 8192);

  const int t = threadIdx.x;
  const int lane = t & 63;
  const int wv = t >> 6;
  const int l15 = lane & 15, l4 = lane >> 4;

  const unsigned short* ApA = A + (size_t)(bm0 + wv * 32 + (lane >> 2)) * 512 + (lane & 3) * 8;
  const unsigned short* ApB = ApA + (size_t)16 * 512;
  unsigned short* lA0a = &As0[(wv * 2 + 0) * 512];
  unsigned short* lA0b = &As0[(wv * 2 + 1) * 512];
  unsigned short* lA1a = &As1[(wv * 2 + 0) * 512];
  unsigned short* lA1b = &As1[(wv * 2 + 1) * 512];

  const unsigned short* Bp[3];
  unsigned short *lB0[3], *lB1[3];
  unsigned short *Bz0[3], *Bz1[3];
#pragma unroll
  for (int z = 0; z < 3; ++z) {
    Bp[z] = wt + (size_t)z * 262144 + (size_t)(bn0 + wv * 16 + (lane >> 2)) * 512 + (lane & 3) * 8;
    Bz0[z] = (unsigned short*)(sm + 16384 + z * 8192);          // [64][32]
    Bz1[z] = (unsigned short*)(sm + 16384 + z * 8192 + 4096);   // [64][32]
    lB0[z] = Bz0[z] + wv * 512;
    lB1[z] = Bz1[z] + wv * 512;
  }

  f32x4 acc[3][2][4];
#pragma unroll
  for (int z = 0; z < 3; ++z)
#pragma unroll
    for (int mi = 0; mi < 2; ++mi)
#pragma unroll
      for (int ni = 0; ni < 4; ++ni) acc[z][mi][ni] = (f32x4){0.f, 0.f, 0.f, 0.f};

  for (int kt = 0; kt < 512; kt += 64) {
    __syncthreads();
    GLOAD_LDS16(ApA + kt, lA0a);
    GLOAD_LDS16(ApA + kt + 32, lA1a);
    GLOAD_LDS16(ApB + kt, lA0b);
    GLOAD_LDS16(ApB + kt + 32, lA1b);
#pragma unroll
    for (int z = 0; z < 3; ++z) {
      GLOAD_LDS16(Bp[z] + kt, lB0[z]);
      GLOAD_LDS16(Bp[z] + kt + 32, lB1[z]);
    }
    __syncthreads();
    bf16x8 af0[2], af1[2];
#pragma unroll
    for (int mi = 0; mi < 2; ++mi) {
      const int r = wv * 32 + mi * 16 + l15;
      af0[mi] = *(const bf16x8*)&As0[r * 32 + l4 * 8];
      af1[mi] = *(const bf16x8*)&As1[r * 32 + l4 * 8];
    }
#pragma unroll
    for (int z = 0; z < 3; ++z) {
      bf16x8 b0[4], b1[4];
#pragma unroll
      for (int ni = 0; ni < 4; ++ni) {
        const int rb = ni * 16 + l15;
        b0[ni] = *(const bf16x8*)&Bz0[z][rb * 32 + l4 * 8];
        b1[ni] = *(const bf16x8*)&Bz1[z][rb * 32 + l4 * 8];
      }
#pragma unroll
      for (int mi = 0; mi < 2; ++mi)
#pragma unroll
        for (int ni = 0; ni < 4; ++ni) {
          acc[z][mi][ni] = __builtin_amdgcn_mfma_f32_16x16x32_bf16(af0[mi], b0[ni], acc[z][mi][ni], 0, 0, 0);
          acc[z][mi][ni] = __builtin_amdgcn_mfma_f32_16x16x32_bf16(af1[mi], b1[ni], acc[z][mi][ni], 0, 0, 0);
        }
    }
  }

  const int b = bm0 >> 12;
  const int nn0 = bm0 & 4095;
  // q and k together: two LDS tiles, one barrier pair, contiguous 16KB stores
  {
    __syncthreads();
    unsigned short (*ct0)[72] = (unsigned short(*)[72])sm;
    unsigned short (*ct1)[72] = (unsigned short(*)[72])(sm + 18432);
#pragma unroll
    for (int mi = 0; mi < 2; ++mi)
#pragma unroll
      for (int ni = 0; ni < 4; ++ni) {
        const int col = ni * 16 + l15;
        const float bbq = bq[bn0 + col];
        const float bbk = bk[bn0 + col];
#pragma unroll
        for (int j = 0; j < 4; ++j) {
          const int row = wv * 32 + mi * 16 + l4 * 4 + j;
          ct0[row][col] = f2bf((acc[0][mi][ni][j] + bbq) * 0.125f);
          ct1[row][col] = f2bf(acc[1][mi][ni][j] + bbk);
        }
      }
    __syncthreads();
    unsigned short* opq = qkv + ((size_t)(b * NH + bn) * SEQ + nn0) * HD;
    unsigned short* opk = opq + 4194304;
#pragma unroll
    for (int r = 0; r < 4; ++r) {
      const int idx = r * 256 + t;       // 0..1023
      const int tok = idx >> 3, part = idx & 7;
      *(uint4*)&opq[(size_t)tok * HD + part * 8] = *(const uint4*)&ct0[tok][part * 8];
      *(uint4*)&opk[(size_t)tok * HD + part * 8] = *(const uint4*)&ct1[tok][part * 8];
    }
  }
  // v (z=2): transposed (B*H, 64, N) direct stores (coalesced along n)
  {
    unsigned short* op = qkv + (size_t)2 * 4194304;
#pragma unroll
    for (int mi = 0; mi < 2; ++mi)
#pragma unroll
      for (int ni = 0; ni < 4; ++ni) {
        const int dd = ni * 16 + l15;
        const float bb = bv[bn0 + dd];
        ushort4 o4;
        o4.x = f2bf(acc[2][mi][ni][0] + bb);
        o4.y = f2bf(acc[2][mi][ni][1] + bb);
        o4.z = f2bf(acc[2][mi][ni][2] + bb);
        o4.w = f2bf(acc[2][mi][ni][3] + bb);
        const int gm0 = bm0 + wv * 32 + mi * 16 + l4 * 4;
        const int nn = gm0 & 4095;
        *(ushort4*)&op[((size_t)(b * NH + bn) * HD + dd) * SEQ + nn] = o4;
      }
  }
}

// ---- fused attention + output projection ----
// Grid (128, 2): block = 32 tokens x batch, 512 threads = 8 waves = 8 heads.
// Per wave (head h = wv): QK^T banded (12 MFMA 32x32x16), softmax in C-frags,
// P -> per-wave LDS slice, PV (12 MFMA) -> ctx 32x64 in regs; barrier;
// ctx -> shared [32][514] bf16 tile (odd dword row-stride: conflict-free
// column reads); barrier; each wave computes out[32 tok][wv*64..+64) =
// ctx @ Wo-slice + bo (64 MFMA, A from LDS, B from L2-resident wt).
__global__ __launch_bounds__(512) void attn_o_kernel(
    const unsigned short* __restrict__ qb, const unsigned short* __restrict__ kb,
    const unsigned short* __restrict__ vt, const unsigned short* __restrict__ wo,
    const float* __restrict__ bo,
    float* __restrict__ attn_out, float* __restrict__ out) {
  // union: per-wave Pl [32][104] bf16 (8 x 6656 B = 53248) / ctx [32][514] bf16 (32896 B)
  __shared__ __align__(16) unsigned char sm[53248];
  const int t = threadIdx.x;
  const int lane = t & 63;
  const int wv = t >> 6;              // 0..7 = head
  const int l31 = lane & 31;
  const int hi = lane >> 5;
  const int b = blockIdx.y;
  const int q0 = blockIdx.x * 32;     // token base
  const int bh = b * NH + wv;
  const int kbase = q0 - 32;
  const size_t base = (size_t)bh * SEQ * HD;

  unsigned short (*Pl)[104] = (unsigned short(*)[104])(sm + wv * 6656);

  // ---- hoisted loads: Q A-frags + V B-frags ----
  bf16x8 aq[4];
#pragma unroll
  for (int kc = 0; kc < 4; ++kc)
    aq[kc] = *(const bf16x8*)&qb[base + (size_t)(q0 + l31) * HD + kc * 16 + hi * 8];

  bf16x8 bvf[2][6];
#pragma unroll
  for (int ks = 0; ks < 6; ++ks) {
    const int key0 = kbase + ks * 16 + hi * 8;
    const bool inr = (key0 >= 0 && key0 < SEQ);
    const int ksafe = inr ? key0 : 0;
#pragma unroll
    for (int dt = 0; dt < 2; ++dt) {
      bf16x8 v = *(const bf16x8*)&vt[((size_t)bh * HD + dt * 32 + l31) * SEQ + ksafe];
      bvf[dt][ks] = inr ? v : (bf16x8){0, 0, 0, 0, 0, 0, 0, 0};
    }
  }

  // ---- QK^T: 3 col-tiles of 32 keys (q pre-scaled by 1/8) ----
  f32x16 acc[3];
#pragma unroll
  for (int ct = 0; ct < 3; ++ct) {
#pragma unroll
    for (int r = 0; r < 16; ++r) acc[ct][r] = 0.f;
    const int krow = kbase + ct * 32 + l31;
    bf16x8 bk[4];
    if (krow >= 0 && krow < SEQ) {
#pragma unroll
      for (int kc = 0; kc < 4; ++kc)
        bk[kc] = *(const bf16x8*)&kb[base + (size_t)krow * HD + kc * 16 + hi * 8];
    } else {
#pragma unroll
      for (int kc = 0; kc < 4; ++kc) bk[kc] = (bf16x8){0, 0, 0, 0, 0, 0, 0, 0};
    }
#pragma unroll
    for (int kc = 0; kc < 4; ++kc)
      acc[ct] = __builtin_amdgcn_mfma_f32_32x32x16_bf16(aq[kc], bk[kc], acc[ct], 0, 0, 0);
  }

  // ---- softmax over w = key - i in [0,64]; i = (r&3)+8*(r>>2)+4*hi ----
#pragma unroll
  for (int ct = 0; ct < 3; ++ct)
#pragma unroll
    for (int r = 0; r < 16; ++r) {
      const int i = (r & 3) + 8 * (r >> 2) + 4 * hi;
      const int w = ct * 32 + l31 - i;
      if (!(w >= 0 && w <= 64)) acc[ct][r] = -3.0e38f;
    }
  float m16[16], inv16[16];
#pragma unroll
  for (int r = 0; r < 16; ++r) {
    float m = fmaxf(fmaxf(acc[0][r], acc[1][r]), acc[2][r]);
#pragma unroll
    for (int o = 16; o; o >>= 1) m = fmaxf(m, __shfl_xor(m, o));
    m16[r] = m;
  }
#pragma unroll
  for (int ct = 0; ct < 3; ++ct)
#pragma unroll
    for (int r = 0; r < 16; ++r)
      acc[ct][r] = (acc[ct][r] > -1.0e38f) ? __expf(acc[ct][r] - m16[r]) : 0.f;
#pragma unroll
  for (int r = 0; r < 16; ++r) {
    float s = acc[0][r] + acc[1][r] + acc[2][r];
#pragma unroll
    for (int o = 16; o; o >>= 1) s += __shfl_xor(s, o);
    inv16[r] = 1.f / s;
  }
#pragma unroll
  for (int ct = 0; ct < 3; ++ct)
#pragma unroll
    for (int r = 0; r < 16; ++r)
      acc[ct][r] *= inv16[r];

  // ---- P -> bf16 LDS (own slice) + attn_out stores from registers ----
  const size_t abase = (size_t)bh * SEQ;
#pragma unroll
  for (int ct = 0; ct < 3; ++ct)
#pragma unroll
    for (int r = 0; r < 16; ++r) {
      const int i = (r & 3) + 8 * (r >> 2) + 4 * hi;
      const int w = ct * 32 + l31 - i;
      const float a = acc[ct][r];
      Pl[i][ct * 32 + l31] = f2bf(a);
      if (w >= 0 && w <= 64)
        attn_out[(abase + q0 + i) * WIN + w] = a;
    }

  // ---- PV: ctx[i][d] = sum_k P[i][k] * V[kbase+k][d] ----
  f32x16 accp[2];
#pragma unroll
  for (int dt = 0; dt < 2; ++dt)
#pragma unroll
    for (int r = 0; r < 16; ++r) accp[dt][r] = 0.f;
#pragma unroll
  for (int ks = 0; ks < 6; ++ks) {
    const bf16x8 pa = *(const bf16x8*)&Pl[l31][ks * 16 + hi * 8];
#pragma unroll
    for (int dt = 0; dt < 2; ++dt)
      accp[dt] = __builtin_amdgcn_mfma_f32_32x32x16_bf16(pa, bvf[dt][ks], accp[dt], 0, 0, 0);
  }

  // ---- ctx -> shared [32][514] tile (all waves), then out-projection ----
  __syncthreads();                       // all waves done reading Pl
  unsigned short (*cl)[514] = (unsigned short(*)[514])sm;
#pragma unroll
  for (int dt = 0; dt < 2; ++dt)
#pragma unroll
    for (int r = 0; r < 16; ++r) {
      const int i = (r & 3) + 8 * (r >> 2) + 4 * hi;
      cl[i][wv * 64 + dt * 32 + l31] = f2bf(accp[dt][r]);
    }
  __syncthreads();                       // ctx tile complete

  // out[q0+i][wv*64 + nt*32 + l31] = sum_k ctx[i][k] * Wo[wv*64+...][k] + bo
  const unsigned short* Bw = wo + (size_t)(wv * 64) * 512;
  f32x16 acco[2];
#pragma unroll
  for (int nt = 0; nt < 2; ++nt)
#pragma unroll
    for (int r = 0; r < 16; ++r) acco[nt][r] = 0.f;
#pragma unroll
  for (int ks = 0; ks < 32; ++ks) {
    const bf16x8 af = *(const bf16x8*)&cl[l31][ks * 16 + hi * 8];
#pragma unroll
    for (int nt = 0; nt < 2; ++nt) {
      const bf16x8 bf = *(const bf16x8*)&Bw[(size_t)(nt * 32 + l31) * 512 + ks * 16 + hi * 8];
      acco[nt] = __builtin_amdgcn_mfma_f32_32x32x16_bf16(af, bf, acco[nt], 0, 0, 0);
    }
  }
  const float bo0 = bo[wv * 64 + l31];
  const float bo1 = bo[wv * 64 + 32 + l31];
#pragma unroll
  for (int nt = 0; nt < 2; ++nt) {
    const float bb = nt ? bo1 : bo0;
#pragma unroll
    for (int r = 0; r < 16; ++r) {
      const int i = (r & 3) + 8 * (r >> 2) + 4 * hi;
      out[((size_t)(b * SEQ + q0 + i)) * DM + wv * 64 + nt * 32 + l31] = acco[nt][r] + bb;
    }
  }
}

extern "C" void kernel_launch(void* const* d_in, const int* in_sizes, int n_in,
                              void* d_out, int out_size, void* d_ws, size_t ws_size,
                              hipStream_t stream) {
  const float* x  = (const float*)d_in[0];
  const float* Wq = (const float*)d_in[1];
  const float* Wk = (const float*)d_in[2];
  const float* Wv = (const float*)d_in[3];
  const float* Wo = (const float*)d_in[4];
  const float* bq = (const float*)d_in[5];
  const float* bk = (const float*)d_in[6];
  const float* bv = (const float*)d_in[7];
  const float* bo = (const float*)d_in[8];

  float* out = (float*)d_out;                        // (B, N, 512) f32
  float* attn_out = out + (size_t)8192 * 512;        // (B, H, N, 65) f32

  char* ws = (char*)d_ws;
  unsigned short* xb   = (unsigned short*)ws;                       // 8,388,608 B
  unsigned short* wt   = (unsigned short*)(ws + 8388608);           // 2,097,152 B
  unsigned short* qkv  = (unsigned short*)(ws + 10485760);          // 25,165,824 B

  prep_kernel<<<dim3(4352), dim3(256), 0, stream>>>(x, xb, Wq, Wk, Wv, Wo, wt);
  gemm_qkv_kernel<<<dim3(512), dim3(256), 0, stream>>>(xb, wt, bq, bk, bv, qkv);
  attn_o_kernel<<<dim3(128, 2), dim3(512), 0, stream>>>(
      qkv, qkv + 4194304, qkv + 8388608, wt + 3 * 262144, bo, attn_out, out);
}

// Round 16
// 60.991 us; speedup vs baseline: 1.0949x; 1.0949x over previous
//
#include <hip/hip_runtime.h>
#include <hip/hip_bf16.h>
#include <stdint.h>

#define SEQ 4096
#define DM 512
#define NH 8
#define HD 64
#define WIN 65

typedef __attribute__((ext_vector_type(8))) short bf16x8;
typedef __attribute__((ext_vector_type(4))) float f32x4;
typedef __attribute__((ext_vector_type(16))) float f32x16;

#define GLOAD_LDS16(gp, lp)                                                 \
  __builtin_amdgcn_global_load_lds(                                         \
      (const __attribute__((address_space(1))) void*)(gp),                  \
      (__attribute__((address_space(3))) void*)(lp), 16, 0, 0)

__device__ __forceinline__ unsigned short f2bf(float f) {
  unsigned int u = __float_as_uint(f);
  u += 0x7FFFu + ((u >> 16) & 1u);
  return (unsigned short)(u >> 16);
}

// ---- fused prep: convert x (f32->bf16) and transpose+convert all 4 W ----
__global__ __launch_bounds__(256) void prep_kernel(
    const float* __restrict__ x, unsigned short* __restrict__ xb,
    const float* __restrict__ w0, const float* __restrict__ w1,
    const float* __restrict__ w2, const float* __restrict__ w3,
    unsigned short* __restrict__ wt) {
  __shared__ float tl[64][65];
  const int bid = blockIdx.x;
  const int t = threadIdx.x;
  if (bid < 4096) {
    const int i = bid * 256 + t;
    float4 v = ((const float4*)x)[i];
    ushort4 o;
    o.x = f2bf(v.x); o.y = f2bf(v.y); o.z = f2bf(v.z); o.w = f2bf(v.w);
    ((ushort4*)xb)[i] = o;
    return;
  }
  const int wtid = bid - 4096;          // [0,256)
  const int z = wtid >> 6;
  const int rem = wtid & 63;
  const int k0 = (rem >> 3) * 64;
  const int n0 = (rem & 7) * 64;
  const float* W = (z == 0) ? w0 : (z == 1) ? w1 : (z == 2) ? w2 : w3;
  unsigned short* o = wt + (size_t)z * 262144;
#pragma unroll
  for (int i = 0; i < 16; ++i) {
    int idx = t + i * 256;
    int r = idx >> 6, c = idx & 63;
    tl[c][r] = W[(size_t)(k0 + r) * 512 + n0 + c];
  }
  __syncthreads();
#pragma unroll
  for (int i = 0; i < 16; ++i) {
    int idx = t + i * 256;
    int r = idx >> 6, c = idx & 63;
    o[(size_t)(n0 + r) * 512 + k0 + c] = f2bf(tl[r][c]);
  }
}

// ---- z-merged QKV GEMM: one block computes q,k,v for (128 tokens x 1 head) ----
// A staged ONCE per K-step; 48 MFMA per barrier-pair. BK=64 dual buffers,
// global_load_lds(16B), linear LDS. q pre-scaled 1/8. Epilogue: q+k staged in
// ONE barrier-pair (two [128][72] tiles in the smem union), v direct.
__global__ __launch_bounds__(256) void gemm_qkv_kernel(
    const unsigned short* __restrict__ A,
    const unsigned short* __restrict__ wt,
    const float* __restrict__ bq, const float* __restrict__ bk, const float* __restrict__ bv,
    unsigned short* __restrict__ qkv) {
  const int bid = blockIdx.x;
  const int bm = bid & 63;
  const int bn = bid >> 6;            // head 0..7
  const int bm0 = bm * 128;
  const int bn0 = bn * 64;

  __shared__ __align__(16) unsigned char sm[40960];
  unsigned short* As0 = (unsigned short*)sm;                 // [128][32]
  unsigned short* As1 = (unsigned short*)(sm + 8192);

  const int t = threadIdx.x;
  const int lane = t & 63;
  const int wv = t >> 6;
  const int l15 = lane & 15, l4 = lane >> 4;

  const unsigned short* ApA = A + (size_t)(bm0 + wv * 32 + (lane >> 2)) * 512 + (lane & 3) * 8;
  const unsigned short* ApB = ApA + (size_t)16 * 512;
  unsigned short* lA0a = &As0[(wv * 2 + 0) * 512];
  unsigned short* lA0b = &As0[(wv * 2 + 1) * 512];
  unsigned short* lA1a = &As1[(wv * 2 + 0) * 512];
  unsigned short* lA1b = &As1[(wv * 2 + 1) * 512];

  const unsigned short* Bp[3];
  unsigned short *lB0[3], *lB1[3];
  unsigned short *Bz0[3], *Bz1[3];
#pragma unroll
  for (int z = 0; z < 3; ++z) {
    Bp[z] = wt + (size_t)z * 262144 + (size_t)(bn0 + wv * 16 + (lane >> 2)) * 512 + (lane & 3) * 8;
    Bz0[z] = (unsigned short*)(sm + 16384 + z * 8192);          // [64][32]
    Bz1[z] = (unsigned short*)(sm + 16384 + z * 8192 + 4096);   // [64][32]
    lB0[z] = Bz0[z] + wv * 512;
    lB1[z] = Bz1[z] + wv * 512;
  }

  f32x4 acc[3][2][4];
#pragma unroll
  for (int z = 0; z < 3; ++z)
#pragma unroll
    for (int mi = 0; mi < 2; ++mi)
#pragma unroll
      for (int ni = 0; ni < 4; ++ni) acc[z][mi][ni] = (f32x4){0.f, 0.f, 0.f, 0.f};

  for (int kt = 0; kt < 512; kt += 64) {
    __syncthreads();
    GLOAD_LDS16(ApA + kt, lA0a);
    GLOAD_LDS16(ApA + kt + 32, lA1a);
    GLOAD_LDS16(ApB + kt, lA0b);
    GLOAD_LDS16(ApB + kt + 32, lA1b);
#pragma unroll
    for (int z = 0; z < 3; ++z) {
      GLOAD_LDS16(Bp[z] + kt, lB0[z]);
      GLOAD_LDS16(Bp[z] + kt + 32, lB1[z]);
    }
    __syncthreads();
    bf16x8 af0[2], af1[2];
#pragma unroll
    for (int mi = 0; mi < 2; ++mi) {
      const int r = wv * 32 + mi * 16 + l15;
      af0[mi] = *(const bf16x8*)&As0[r * 32 + l4 * 8];
      af1[mi] = *(const bf16x8*)&As1[r * 32 + l4 * 8];
    }
#pragma unroll
    for (int z = 0; z < 3; ++z) {
      bf16x8 b0[4], b1[4];
#pragma unroll
      for (int ni = 0; ni < 4; ++ni) {
        const int rb = ni * 16 + l15;
        b0[ni] = *(const bf16x8*)&Bz0[z][rb * 32 + l4 * 8];
        b1[ni] = *(const bf16x8*)&Bz1[z][rb * 32 + l4 * 8];
      }
#pragma unroll
      for (int mi = 0; mi < 2; ++mi)
#pragma unroll
        for (int ni = 0; ni < 4; ++ni) {
          acc[z][mi][ni] = __builtin_amdgcn_mfma_f32_16x16x32_bf16(af0[mi], b0[ni], acc[z][mi][ni], 0, 0, 0);
          acc[z][mi][ni] = __builtin_amdgcn_mfma_f32_16x16x32_bf16(af1[mi], b1[ni], acc[z][mi][ni], 0, 0, 0);
        }
    }
  }

  const int b = bm0 >> 12;
  const int nn0 = bm0 & 4095;
  // q and k together: two LDS tiles, one barrier pair, contiguous 16KB stores
  {
    __syncthreads();
    unsigned short (*ct0)[72] = (unsigned short(*)[72])sm;
    unsigned short (*ct1)[72] = (unsigned short(*)[72])(sm + 18432);
#pragma unroll
    for (int mi = 0; mi < 2; ++mi)
#pragma unroll
      for (int ni = 0; ni < 4; ++ni) {
        const int col = ni * 16 + l15;
        const float bbq = bq[bn0 + col];
        const float bbk = bk[bn0 + col];
#pragma unroll
        for (int j = 0; j < 4; ++j) {
          const int row = wv * 32 + mi * 16 + l4 * 4 + j;
          ct0[row][col] = f2bf((acc[0][mi][ni][j] + bbq) * 0.125f);
          ct1[row][col] = f2bf(acc[1][mi][ni][j] + bbk);
        }
      }
    __syncthreads();
    unsigned short* opq = qkv + ((size_t)(b * NH + bn) * SEQ + nn0) * HD;
    unsigned short* opk = opq + 4194304;
#pragma unroll
    for (int r = 0; r < 4; ++r) {
      const int idx = r * 256 + t;       // 0..1023
      const int tok = idx >> 3, part = idx & 7;
      *(uint4*)&opq[(size_t)tok * HD + part * 8] = *(const uint4*)&ct0[tok][part * 8];
      *(uint4*)&opk[(size_t)tok * HD + part * 8] = *(const uint4*)&ct1[tok][part * 8];
    }
  }
  // v (z=2): transposed (B*H, 64, N) direct stores (coalesced along n)
  {
    unsigned short* op = qkv + (size_t)2 * 4194304;
#pragma unroll
    for (int mi = 0; mi < 2; ++mi)
#pragma unroll
      for (int ni = 0; ni < 4; ++ni) {
        const int dd = ni * 16 + l15;
        const float bb = bv[bn0 + dd];
        ushort4 o4;
        o4.x = f2bf(acc[2][mi][ni][0] + bb);
        o4.y = f2bf(acc[2][mi][ni][1] + bb);
        o4.z = f2bf(acc[2][mi][ni][2] + bb);
        o4.w = f2bf(acc[2][mi][ni][3] + bb);
        const int gm0 = bm0 + wv * 32 + mi * 16 + l4 * 4;
        const int nn = gm0 & 4095;
        *(ushort4*)&op[((size_t)(b * NH + bn) * HD + dd) * SEQ + nn] = o4;
      }
  }
}

// ---- Wo GEMM: BM=64, grid 512, f32 out, LDS-staged epilogue ----
__global__ __launch_bounds__(256) void gemm_o_kernel(
    const unsigned short* __restrict__ A,
    const unsigned short* __restrict__ wt,
    const float* __restrict__ bias,
    float* __restrict__ outp) {
  const int bid = blockIdx.x;
  const int bm = bid & 127;
  const int bn = bid >> 7;
  const int bm0 = bm * 64;
  const int bn0 = bn * 128;
  const unsigned short* W = wt;

  __shared__ __align__(16) unsigned char sm[33792];
  unsigned short* As0 = (unsigned short*)sm;                    // [64][32]
  unsigned short* As1 = (unsigned short*)(sm + 4096);
  unsigned short* Bs0 = (unsigned short*)(sm + 8192);           // [128][32]
  unsigned short* Bs1 = (unsigned short*)(sm + 16384);

  const int t = threadIdx.x;
  const int lane = t & 63;
  const int wv = t >> 6;
  const int wr = wv >> 1, wc = wv & 1;
  const int l15 = lane & 15, l4 = lane >> 4;

  const unsigned short* ApA = A + (size_t)(bm0 + wv * 16 + (lane >> 2)) * 512 + (lane & 3) * 8;
  unsigned short* lA0a = &As0[wv * 512];
  unsigned short* lA1a = &As1[wv * 512];
  const unsigned short* BpA = W + (size_t)(bn0 + wv * 32 + (lane >> 2)) * 512 + (lane & 3) * 8;
  const unsigned short* BpB = BpA + (size_t)16 * 512;
  unsigned short* lB0a = &Bs0[(wv * 2 + 0) * 512];
  unsigned short* lB0b = &Bs0[(wv * 2 + 1) * 512];
  unsigned short* lB1a = &Bs1[(wv * 2 + 0) * 512];
  unsigned short* lB1b = &Bs1[(wv * 2 + 1) * 512];

  f32x4 acc[2][4];
#pragma unroll
  for (int i = 0; i < 2; ++i)
#pragma unroll
    for (int j = 0; j < 4; ++j) acc[i][j] = (f32x4){0.f, 0.f, 0.f, 0.f};

  for (int kt = 0; kt < 512; kt += 64) {
    __syncthreads();
    GLOAD_LDS16(ApA + kt, lA0a);
    GLOAD_LDS16(ApA + kt + 32, lA1a);
    GLOAD_LDS16(BpA + kt, lB0a);
    GLOAD_LDS16(BpA + kt + 32, lB1a);
    GLOAD_LDS16(BpB + kt, lB0b);
    GLOAD_LDS16(BpB + kt + 32, lB1b);
    __syncthreads();
    bf16x8 af0[2], af1[2], bf0[4], bf1[4];
#pragma unroll
    for (int mi = 0; mi < 2; ++mi) {
      const int r = wr * 32 + mi * 16 + l15;
      af0[mi] = *(const bf16x8*)&As0[r * 32 + l4 * 8];
      af1[mi] = *(const bf16x8*)&As1[r * 32 + l4 * 8];
    }
#pragma unroll
    for (int ni = 0; ni < 4; ++ni) {
      const int r = wc * 64 + ni * 16 + l15;
      bf0[ni] = *(const bf16x8*)&Bs0[r * 32 + l4 * 8];
      bf1[ni] = *(const bf16x8*)&Bs1[r * 32 + l4 * 8];
    }
#pragma unroll
    for (int mi = 0; mi < 2; ++mi)
#pragma unroll
      for (int ni = 0; ni < 4; ++ni) {
        acc[mi][ni] = __builtin_amdgcn_mfma_f32_16x16x32_bf16(af0[mi], bf0[ni], acc[mi][ni], 0, 0, 0);
        acc[mi][ni] = __builtin_amdgcn_mfma_f32_16x16x32_bf16(af1[mi], bf1[ni], acc[mi][ni], 0, 0, 0);
      }
  }

  __syncthreads();
  float (*cf)[132] = (float(*)[132])sm;
#pragma unroll
  for (int mi = 0; mi < 2; ++mi)
#pragma unroll
    for (int ni = 0; ni < 4; ++ni) {
      const int gn = bn0 + wc * 64 + ni * 16 + l15;
      const float bb = bias[gn];
#pragma unroll
      for (int j = 0; j < 4; ++j)
        cf[wr * 32 + mi * 16 + l4 * 4 + j][wc * 64 + ni * 16 + l15] = acc[mi][ni][j] + bb;
    }
  __syncthreads();
  float* op = outp + (size_t)bm0 * 512 + bn0;
#pragma unroll
  for (int r = 0; r < 8; ++r) {
    const int idx = r * 256 + t;           // 0..2047
    const int tok = idx >> 5;              // 0..63
    const int part = idx & 31;
    *(float4*)&op[(size_t)tok * 512 + part * 4] = *(const float4*)&cf[tok][part * 4];
  }
}

// ---- MFMA local attention, 32x32x16 (R12/R14-proven version) ----
__global__ __launch_bounds__(256) void attn_kernel(
    const unsigned short* __restrict__ qb, const unsigned short* __restrict__ kb,
    const unsigned short* __restrict__ vt,
    float* __restrict__ attn_out, unsigned short* __restrict__ ctxb) {
  __shared__ unsigned short Pl[4][32][104];   // bf16 P, rows=query, cols=key 0..95
  const int t = threadIdx.x;
  const int lane = t & 63;
  const int wv = t >> 6;              // 0..3
  const int l31 = lane & 31;
  const int hi = lane >> 5;
  const int bh = blockIdx.y;
  const int q0 = blockIdx.x * 128 + wv * 32;
  const int kbase = q0 - 32;
  const size_t base = (size_t)bh * SEQ * HD;

  bf16x8 aq[4];
#pragma unroll
  for (int kc = 0; kc < 4; ++kc)
    aq[kc] = *(const bf16x8*)&qb[base + (size_t)(q0 + l31) * HD + kc * 16 + hi * 8];

  bf16x8 bvf[2][6];
#pragma unroll
  for (int ks = 0; ks < 6; ++ks) {
    const int key0 = kbase + ks * 16 + hi * 8;
    const bool inr = (key0 >= 0 && key0 < SEQ);
    const int ksafe = inr ? key0 : 0;
#pragma unroll
    for (int dt = 0; dt < 2; ++dt) {
      bf16x8 v = *(const bf16x8*)&vt[((size_t)bh * HD + dt * 32 + l31) * SEQ + ksafe];
      bvf[dt][ks] = inr ? v : (bf16x8){0, 0, 0, 0, 0, 0, 0, 0};
    }
  }

  f32x16 acc[3];
#pragma unroll
  for (int ct = 0; ct < 3; ++ct) {
#pragma unroll
    for (int r = 0; r < 16; ++r) acc[ct][r] = 0.f;
    const int krow = kbase + ct * 32 + l31;
    bf16x8 bk[4];
    if (krow >= 0 && krow < SEQ) {
#pragma unroll
      for (int kc = 0; kc < 4; ++kc)
        bk[kc] = *(const bf16x8*)&kb[base + (size_t)krow * HD + kc * 16 + hi * 8];
    } else {
#pragma unroll
      for (int kc = 0; kc < 4; ++kc) bk[kc] = (bf16x8){0, 0, 0, 0, 0, 0, 0, 0};
    }
#pragma unroll
    for (int kc = 0; kc < 4; ++kc)
      acc[ct] = __builtin_amdgcn_mfma_f32_32x32x16_bf16(aq[kc], bk[kc], acc[ct], 0, 0, 0);
  }

#pragma unroll
  for (int ct = 0; ct < 3; ++ct)
#pragma unroll
    for (int r = 0; r < 16; ++r) {
      const int i = (r & 3) + 8 * (r >> 2) + 4 * hi;
      const int w = ct * 32 + l31 - i;
      if (!(w >= 0 && w <= 64)) acc[ct][r] = -3.0e38f;
    }
  float m16[16], inv16[16];
#pragma unroll
  for (int r = 0; r < 16; ++r) {
    float m = fmaxf(fmaxf(acc[0][r], acc[1][r]), acc[2][r]);
#pragma unroll
    for (int o = 16; o; o >>= 1) m = fmaxf(m, __shfl_xor(m, o));
    m16[r] = m;
  }
#pragma unroll
  for (int ct = 0; ct < 3; ++ct)
#pragma unroll
    for (int r = 0; r < 16; ++r)
      acc[ct][r] = (acc[ct][r] > -1.0e38f) ? __expf(acc[ct][r] - m16[r]) : 0.f;
#pragma unroll
  for (int r = 0; r < 16; ++r) {
    float s = acc[0][r] + acc[1][r] + acc[2][r];
#pragma unroll
    for (int o = 16; o; o >>= 1) s += __shfl_xor(s, o);
    inv16[r] = 1.f / s;
  }
#pragma unroll
  for (int ct = 0; ct < 3; ++ct)
#pragma unroll
    for (int r = 0; r < 16; ++r)
      acc[ct][r] *= inv16[r];

  const size_t abase = (size_t)bh * SEQ;
#pragma unroll
  for (int ct = 0; ct < 3; ++ct)
#pragma unroll
    for (int r = 0; r < 16; ++r) {
      const int i = (r & 3) + 8 * (r >> 2) + 4 * hi;
      const int w = ct * 32 + l31 - i;
      const float a = acc[ct][r];
      Pl[wv][i][ct * 32 + l31] = f2bf(a);
      if (w >= 0 && w <= 64)
        attn_out[(abase + q0 + i) * WIN + w] = a;
    }

  f32x16 accp[2];
#pragma unroll
  for (int dt = 0; dt < 2; ++dt)
#pragma unroll
    for (int r = 0; r < 16; ++r) accp[dt][r] = 0.f;
#pragma unroll
  for (int ks = 0; ks < 6; ++ks) {
    const bf16x8 pa = *(const bf16x8*)&Pl[wv][l31][ks * 16 + hi * 8];
#pragma unroll
    for (int dt = 0; dt < 2; ++dt)
      accp[dt] = __builtin_amdgcn_mfma_f32_32x32x16_bf16(pa, bvf[dt][ks], accp[dt], 0, 0, 0);
  }

  const int b = bh >> 3, h = bh & 7;
  {
    asm volatile("s_waitcnt lgkmcnt(0)" ::: "memory");   // pa reads drained (WAR)
    unsigned short (*ctw)[72] = (unsigned short(*)[72])((unsigned char*)&Pl[wv][0][0]);
#pragma unroll
    for (int dt = 0; dt < 2; ++dt)
#pragma unroll
      for (int r = 0; r < 16; ++r) {
        const int i = (r & 3) + 8 * (r >> 2) + 4 * hi;
        ctw[i][dt * 32 + l31] = f2bf(accp[dt][r]);
      }
    asm volatile("s_waitcnt lgkmcnt(0)" ::: "memory");   // writes visible (RAW)
    unsigned short* cp = &ctxb[((size_t)(b * SEQ + q0)) * DM + h * HD];
#pragma unroll
    for (int it = 0; it < 4; ++it) {
      const int idx = it * 64 + lane;    // 0..255: tok = idx>>3, part = idx&7
      const int tok = idx >> 3, part = idx & 7;
      *(uint4*)&cp[(size_t)tok * DM + part * 8] = *(const uint4*)&ctw[tok][part * 8];
    }
  }
}

extern "C" void kernel_launch(void* const* d_in, const int* in_sizes, int n_in,
                              void* d_out, int out_size, void* d_ws, size_t ws_size,
                              hipStream_t stream) {
  const float* x  = (const float*)d_in[0];
  const float* Wq = (const float*)d_in[1];
  const float* Wk = (const float*)d_in[2];
  const float* Wv = (const float*)d_in[3];
  const float* Wo = (const float*)d_in[4];
  const float* bq = (const float*)d_in[5];
  const float* bk = (const float*)d_in[6];
  const float* bv = (const float*)d_in[7];
  const float* bo = (const float*)d_in[8];

  float* out = (float*)d_out;                        // (B, N, 512) f32
  float* attn_out = out + (size_t)8192 * 512;        // (B, H, N, 65) f32

  char* ws = (char*)d_ws;
  unsigned short* xb   = (unsigned short*)ws;                       // 8,388,608 B
  unsigned short* wt   = (unsigned short*)(ws + 8388608);           // 2,097,152 B
  unsigned short* qkv  = (unsigned short*)(ws + 10485760);          // 25,165,824 B
  unsigned short* ctxb = (unsigned short*)(ws + 35651584);          // 8,388,608 B

  prep_kernel<<<dim3(4352), dim3(256), 0, stream>>>(x, xb, Wq, Wk, Wv, Wo, wt);
  gemm_qkv_kernel<<<dim3(512), dim3(256), 0, stream>>>(xb, wt, bq, bk, bv, qkv);
  attn_kernel<<<dim3(32, 16), dim3(256), 0, stream>>>(
      qkv, qkv + 4194304, qkv + 8388608, attn_out, ctxb);
  gemm_o_kernel<<<dim3(512), dim3(256), 0, stream>>>(ctxb, wt + 3 * 262144, bo, out);
}

// Round 17
// 60.351 us; speedup vs baseline: 1.1065x; 1.0106x over previous
//
#include <hip/hip_runtime.h>
#include <hip/hip_bf16.h>
#include <stdint.h>

#define SEQ 4096
#define DM 512
#define NH 8
#define HD 64
#define WIN 65

typedef __attribute__((ext_vector_type(8))) short bf16x8;
typedef __attribute__((ext_vector_type(4))) float f32x4;
typedef __attribute__((ext_vector_type(16))) float f32x16;

#define GLOAD_LDS16(gp, lp)                                                 \
  __builtin_amdgcn_global_load_lds(                                         \
      (const __attribute__((address_space(1))) void*)(gp),                  \
      (__attribute__((address_space(3))) void*)(lp), 16, 0, 0)

__device__ __forceinline__ unsigned short f2bf(float f) {
  unsigned int u = __float_as_uint(f);
  u += 0x7FFFu + ((u >> 16) & 1u);
  return (unsigned short)(u >> 16);
}

// ---- fused prep: convert x (f32->bf16) and transpose+convert all 4 W ----
__global__ __launch_bounds__(256) void prep_kernel(
    const float* __restrict__ x, unsigned short* __restrict__ xb,
    const float* __restrict__ w0, const float* __restrict__ w1,
    const float* __restrict__ w2, const float* __restrict__ w3,
    unsigned short* __restrict__ wt) {
  __shared__ float tl[64][65];
  const int bid = blockIdx.x;
  const int t = threadIdx.x;
  if (bid < 4096) {
    const int i = bid * 256 + t;
    float4 v = ((const float4*)x)[i];
    ushort4 o;
    o.x = f2bf(v.x); o.y = f2bf(v.y); o.z = f2bf(v.z); o.w = f2bf(v.w);
    ((ushort4*)xb)[i] = o;
    return;
  }
  const int wtid = bid - 4096;          // [0,256)
  const int z = wtid >> 6;
  const int rem = wtid & 63;
  const int k0 = (rem >> 3) * 64;
  const int n0 = (rem & 7) * 64;
  const float* W = (z == 0) ? w0 : (z == 1) ? w1 : (z == 2) ? w2 : w3;
  unsigned short* o = wt + (size_t)z * 262144;
#pragma unroll
  for (int i = 0; i < 16; ++i) {
    int idx = t + i * 256;
    int r = idx >> 6, c = idx & 63;
    tl[c][r] = W[(size_t)(k0 + r) * 512 + n0 + c];
  }
  __syncthreads();
#pragma unroll
  for (int i = 0; i < 16; ++i) {
    int idx = t + i * 256;
    int r = idx >> 6, c = idx & 63;
    o[(size_t)(n0 + r) * 512 + k0 + c] = f2bf(tl[r][c]);
  }
}

// ---- z-merged QKV GEMM (unchanged, R14-proven) ----
__global__ __launch_bounds__(256) void gemm_qkv_kernel(
    const unsigned short* __restrict__ A,
    const unsigned short* __restrict__ wt,
    const float* __restrict__ bq, const float* __restrict__ bk, const float* __restrict__ bv,
    unsigned short* __restrict__ qkv) {
  const int bid = blockIdx.x;
  const int bm = bid & 63;
  const int bn = bid >> 6;            // head 0..7
  const int bm0 = bm * 128;
  const int bn0 = bn * 64;

  __shared__ __align__(16) unsigned char sm[40960];
  unsigned short* As0 = (unsigned short*)sm;                 // [128][32]
  unsigned short* As1 = (unsigned short*)(sm + 8192);

  const int t = threadIdx.x;
  const int lane = t & 63;
  const int wv = t >> 6;
  const int l15 = lane & 15, l4 = lane >> 4;

  const unsigned short* ApA = A + (size_t)(bm0 + wv * 32 + (lane >> 2)) * 512 + (lane & 3) * 8;
  const unsigned short* ApB = ApA + (size_t)16 * 512;
  unsigned short* lA0a = &As0[(wv * 2 + 0) * 512];
  unsigned short* lA0b = &As0[(wv * 2 + 1) * 512];
  unsigned short* lA1a = &As1[(wv * 2 + 0) * 512];
  unsigned short* lA1b = &As1[(wv * 2 + 1) * 512];

  const unsigned short* Bp[3];
  unsigned short *lB0[3], *lB1[3];
  unsigned short *Bz0[3], *Bz1[3];
#pragma unroll
  for (int z = 0; z < 3; ++z) {
    Bp[z] = wt + (size_t)z * 262144 + (size_t)(bn0 + wv * 16 + (lane >> 2)) * 512 + (lane & 3) * 8;
    Bz0[z] = (unsigned short*)(sm + 16384 + z * 8192);          // [64][32]
    Bz1[z] = (unsigned short*)(sm + 16384 + z * 8192 + 4096);   // [64][32]
    lB0[z] = Bz0[z] + wv * 512;
    lB1[z] = Bz1[z] + wv * 512;
  }

  f32x4 acc[3][2][4];
#pragma unroll
  for (int z = 0; z < 3; ++z)
#pragma unroll
    for (int mi = 0; mi < 2; ++mi)
#pragma unroll
      for (int ni = 0; ni < 4; ++ni) acc[z][mi][ni] = (f32x4){0.f, 0.f, 0.f, 0.f};

  for (int kt = 0; kt < 512; kt += 64) {
    __syncthreads();
    GLOAD_LDS16(ApA + kt, lA0a);
    GLOAD_LDS16(ApA + kt + 32, lA1a);
    GLOAD_LDS16(ApB + kt, lA0b);
    GLOAD_LDS16(ApB + kt + 32, lA1b);
#pragma unroll
    for (int z = 0; z < 3; ++z) {
      GLOAD_LDS16(Bp[z] + kt, lB0[z]);
      GLOAD_LDS16(Bp[z] + kt + 32, lB1[z]);
    }
    __syncthreads();
    bf16x8 af0[2], af1[2];
#pragma unroll
    for (int mi = 0; mi < 2; ++mi) {
      const int r = wv * 32 + mi * 16 + l15;
      af0[mi] = *(const bf16x8*)&As0[r * 32 + l4 * 8];
      af1[mi] = *(const bf16x8*)&As1[r * 32 + l4 * 8];
    }
#pragma unroll
    for (int z = 0; z < 3; ++z) {
      bf16x8 b0[4], b1[4];
#pragma unroll
      for (int ni = 0; ni < 4; ++ni) {
        const int rb = ni * 16 + l15;
        b0[ni] = *(const bf16x8*)&Bz0[z][rb * 32 + l4 * 8];
        b1[ni] = *(const bf16x8*)&Bz1[z][rb * 32 + l4 * 8];
      }
#pragma unroll
      for (int mi = 0; mi < 2; ++mi)
#pragma unroll
        for (int ni = 0; ni < 4; ++ni) {
          acc[z][mi][ni] = __builtin_amdgcn_mfma_f32_16x16x32_bf16(af0[mi], b0[ni], acc[z][mi][ni], 0, 0, 0);
          acc[z][mi][ni] = __builtin_amdgcn_mfma_f32_16x16x32_bf16(af1[mi], b1[ni], acc[z][mi][ni], 0, 0, 0);
        }
    }
  }

  const int b = bm0 >> 12;
  const int nn0 = bm0 & 4095;
  // q and k together: two LDS tiles, one barrier pair, contiguous 16KB stores
  {
    __syncthreads();
    unsigned short (*ct0)[72] = (unsigned short(*)[72])sm;
    unsigned short (*ct1)[72] = (unsigned short(*)[72])(sm + 18432);
#pragma unroll
    for (int mi = 0; mi < 2; ++mi)
#pragma unroll
      for (int ni = 0; ni < 4; ++ni) {
        const int col = ni * 16 + l15;
        const float bbq = bq[bn0 + col];
        const float bbk = bk[bn0 + col];
#pragma unroll
        for (int j = 0; j < 4; ++j) {
          const int row = wv * 32 + mi * 16 + l4 * 4 + j;
          ct0[row][col] = f2bf((acc[0][mi][ni][j] + bbq) * 0.125f);
          ct1[row][col] = f2bf(acc[1][mi][ni][j] + bbk);
        }
      }
    __syncthreads();
    unsigned short* opq = qkv + ((size_t)(b * NH + bn) * SEQ + nn0) * HD;
    unsigned short* opk = opq + 4194304;
#pragma unroll
    for (int r = 0; r < 4; ++r) {
      const int idx = r * 256 + t;       // 0..1023
      const int tok = idx >> 3, part = idx & 7;
      *(uint4*)&opq[(size_t)tok * HD + part * 8] = *(const uint4*)&ct0[tok][part * 8];
      *(uint4*)&opk[(size_t)tok * HD + part * 8] = *(const uint4*)&ct1[tok][part * 8];
    }
  }
  // v (z=2): transposed (B*H, 64, N) direct stores (coalesced along n)
  {
    unsigned short* op = qkv + (size_t)2 * 4194304;
#pragma unroll
    for (int mi = 0; mi < 2; ++mi)
#pragma unroll
      for (int ni = 0; ni < 4; ++ni) {
        const int dd = ni * 16 + l15;
        const float bb = bv[bn0 + dd];
        ushort4 o4;
        o4.x = f2bf(acc[2][mi][ni][0] + bb);
        o4.y = f2bf(acc[2][mi][ni][1] + bb);
        o4.z = f2bf(acc[2][mi][ni][2] + bb);
        o4.w = f2bf(acc[2][mi][ni][3] + bb);
        const int gm0 = bm0 + wv * 32 + mi * 16 + l4 * 4;
        const int nn = gm0 & 4095;
        *(ushort4*)&op[((size_t)(b * NH + bn) * HD + dd) * SEQ + nn] = o4;
      }
  }
}

// ---- Wo GEMM: BM=64, grid 512, f32 out, LDS-staged epilogue (unchanged) ----
__global__ __launch_bounds__(256) void gemm_o_kernel(
    const unsigned short* __restrict__ A,
    const unsigned short* __restrict__ wt,
    const float* __restrict__ bias,
    float* __restrict__ outp) {
  const int bid = blockIdx.x;
  const int bm = bid & 127;
  const int bn = bid >> 7;
  const int bm0 = bm * 64;
  const int bn0 = bn * 128;
  const unsigned short* W = wt;

  __shared__ __align__(16) unsigned char sm[33792];
  unsigned short* As0 = (unsigned short*)sm;                    // [64][32]
  unsigned short* As1 = (unsigned short*)(sm + 4096);
  unsigned short* Bs0 = (unsigned short*)(sm + 8192);           // [128][32]
  unsigned short* Bs1 = (unsigned short*)(sm + 16384);

  const int t = threadIdx.x;
  const int lane = t & 63;
  const int wv = t >> 6;
  const int wr = wv >> 1, wc = wv & 1;
  const int l15 = lane & 15, l4 = lane >> 4;

  const unsigned short* ApA = A + (size_t)(bm0 + wv * 16 + (lane >> 2)) * 512 + (lane & 3) * 8;
  unsigned short* lA0a = &As0[wv * 512];
  unsigned short* lA1a = &As1[wv * 512];
  const unsigned short* BpA = W + (size_t)(bn0 + wv * 32 + (lane >> 2)) * 512 + (lane & 3) * 8;
  const unsigned short* BpB = BpA + (size_t)16 * 512;
  unsigned short* lB0a = &Bs0[(wv * 2 + 0) * 512];
  unsigned short* lB0b = &Bs0[(wv * 2 + 1) * 512];
  unsigned short* lB1a = &Bs1[(wv * 2 + 0) * 512];
  unsigned short* lB1b = &Bs1[(wv * 2 + 1) * 512];

  f32x4 acc[2][4];
#pragma unroll
  for (int i = 0; i < 2; ++i)
#pragma unroll
    for (int j = 0; j < 4; ++j) acc[i][j] = (f32x4){0.f, 0.f, 0.f, 0.f};

  for (int kt = 0; kt < 512; kt += 64) {
    __syncthreads();
    GLOAD_LDS16(ApA + kt, lA0a);
    GLOAD_LDS16(ApA + kt + 32, lA1a);
    GLOAD_LDS16(BpA + kt, lB0a);
    GLOAD_LDS16(BpA + kt + 32, lB1a);
    GLOAD_LDS16(BpB + kt, lB0b);
    GLOAD_LDS16(BpB + kt + 32, lB1b);
    __syncthreads();
    bf16x8 af0[2], af1[2], bf0[4], bf1[4];
#pragma unroll
    for (int mi = 0; mi < 2; ++mi) {
      const int r = wr * 32 + mi * 16 + l15;
      af0[mi] = *(const bf16x8*)&As0[r * 32 + l4 * 8];
      af1[mi] = *(const bf16x8*)&As1[r * 32 + l4 * 8];
    }
#pragma unroll
    for (int ni = 0; ni < 4; ++ni) {
      const int r = wc * 64 + ni * 16 + l15;
      bf0[ni] = *(const bf16x8*)&Bs0[r * 32 + l4 * 8];
      bf1[ni] = *(const bf16x8*)&Bs1[r * 32 + l4 * 8];
    }
#pragma unroll
    for (int mi = 0; mi < 2; ++mi)
#pragma unroll
      for (int ni = 0; ni < 4; ++ni) {
        acc[mi][ni] = __builtin_amdgcn_mfma_f32_16x16x32_bf16(af0[mi], bf0[ni], acc[mi][ni], 0, 0, 0);
        acc[mi][ni] = __builtin_amdgcn_mfma_f32_16x16x32_bf16(af1[mi], bf1[ni], acc[mi][ni], 0, 0, 0);
      }
  }

  __syncthreads();
  float (*cf)[132] = (float(*)[132])sm;
#pragma unroll
  for (int mi = 0; mi < 2; ++mi)
#pragma unroll
    for (int ni = 0; ni < 4; ++ni) {
      const int gn = bn0 + wc * 64 + ni * 16 + l15;
      const float bb = bias[gn];
#pragma unroll
      for (int j = 0; j < 4; ++j)
        cf[wr * 32 + mi * 16 + l4 * 4 + j][wc * 64 + ni * 16 + l15] = acc[mi][ni][j] + bb;
    }
  __syncthreads();
  float* op = outp + (size_t)bm0 * 512 + bn0;
#pragma unroll
  for (int r = 0; r < 8; ++r) {
    const int idx = r * 256 + t;           // 0..2047
    const int tok = idx >> 5;              // 0..63
    const int part = idx & 31;
    *(float4*)&op[(size_t)tok * 512 + part * 4] = *(const float4*)&cf[tok][part * 4];
  }
}

// ---- MFMA local attention, 32x32x16: V loads deferred to post-softmax
// (releases 48 VGPRs across QK/softmax -> higher natural occupancy; NO
// launch_bounds cap), setprio(1) around MFMA clusters (m191 regime:
// independent per-wave chains, no block barriers).
__global__ __launch_bounds__(256) void attn_kernel(
    const unsigned short* __restrict__ qb, const unsigned short* __restrict__ kb,
    const unsigned short* __restrict__ vt,
    float* __restrict__ attn_out, unsigned short* __restrict__ ctxb) {
  __shared__ unsigned short Pl[4][32][104];   // bf16 P, rows=query, cols=key 0..95
  const int t = threadIdx.x;
  const int lane = t & 63;
  const int wv = t >> 6;              // 0..3
  const int l31 = lane & 31;
  const int hi = lane >> 5;
  const int bh = blockIdx.y;
  const int q0 = blockIdx.x * 128 + wv * 32;
  const int kbase = q0 - 32;
  const size_t base = (size_t)bh * SEQ * HD;

  bf16x8 aq[4];
#pragma unroll
  for (int kc = 0; kc < 4; ++kc)
    aq[kc] = *(const bf16x8*)&qb[base + (size_t)(q0 + l31) * HD + kc * 16 + hi * 8];

  f32x16 acc[3];
#pragma unroll
  for (int ct = 0; ct < 3; ++ct) {
#pragma unroll
    for (int r = 0; r < 16; ++r) acc[ct][r] = 0.f;
    const int krow = kbase + ct * 32 + l31;
    bf16x8 bk[4];
    if (krow >= 0 && krow < SEQ) {
#pragma unroll
      for (int kc = 0; kc < 4; ++kc)
        bk[kc] = *(const bf16x8*)&kb[base + (size_t)krow * HD + kc * 16 + hi * 8];
    } else {
#pragma unroll
      for (int kc = 0; kc < 4; ++kc) bk[kc] = (bf16x8){0, 0, 0, 0, 0, 0, 0, 0};
    }
    __builtin_amdgcn_s_setprio(1);
#pragma unroll
    for (int kc = 0; kc < 4; ++kc)
      acc[ct] = __builtin_amdgcn_mfma_f32_32x32x16_bf16(aq[kc], bk[kc], acc[ct], 0, 0, 0);
    __builtin_amdgcn_s_setprio(0);
  }

#pragma unroll
  for (int ct = 0; ct < 3; ++ct)
#pragma unroll
    for (int r = 0; r < 16; ++r) {
      const int i = (r & 3) + 8 * (r >> 2) + 4 * hi;
      const int w = ct * 32 + l31 - i;
      if (!(w >= 0 && w <= 64)) acc[ct][r] = -3.0e38f;
    }
  float m16[16], inv16[16];
#pragma unroll
  for (int r = 0; r < 16; ++r) {
    float m = fmaxf(fmaxf(acc[0][r], acc[1][r]), acc[2][r]);
#pragma unroll
    for (int o = 16; o; o >>= 1) m = fmaxf(m, __shfl_xor(m, o));
    m16[r] = m;
  }
#pragma unroll
  for (int ct = 0; ct < 3; ++ct)
#pragma unroll
    for (int r = 0; r < 16; ++r)
      acc[ct][r] = (acc[ct][r] > -1.0e38f) ? __expf(acc[ct][r] - m16[r]) : 0.f;
#pragma unroll
  for (int r = 0; r < 16; ++r) {
    float s = acc[0][r] + acc[1][r] + acc[2][r];
#pragma unroll
    for (int o = 16; o; o >>= 1) s += __shfl_xor(s, o);
    inv16[r] = 1.f / s;
  }
#pragma unroll
  for (int ct = 0; ct < 3; ++ct)
#pragma unroll
    for (int r = 0; r < 16; ++r)
      acc[ct][r] *= inv16[r];

  // ---- P -> bf16 LDS ----
#pragma unroll
  for (int ct = 0; ct < 3; ++ct)
#pragma unroll
    for (int r = 0; r < 16; ++r) {
      const int i = (r & 3) + 8 * (r >> 2) + 4 * hi;
      Pl[wv][i][ct * 32 + l31] = f2bf(acc[ct][r]);
    }

  // ---- V loads (deferred: issued here, covered by attn_out store burst) ----
  bf16x8 bvf[2][6];
#pragma unroll
  for (int ks = 0; ks < 6; ++ks) {
    const int key0 = kbase + ks * 16 + hi * 8;
    const bool inr = (key0 >= 0 && key0 < SEQ);
    const int ksafe = inr ? key0 : 0;
#pragma unroll
    for (int dt = 0; dt < 2; ++dt) {
      bf16x8 v = *(const bf16x8*)&vt[((size_t)bh * HD + dt * 32 + l31) * SEQ + ksafe];
      bvf[dt][ks] = inr ? v : (bf16x8){0, 0, 0, 0, 0, 0, 0, 0};
    }
  }

  // ---- attn_out stores from registers ----
  const size_t abase = (size_t)bh * SEQ;
#pragma unroll
  for (int ct = 0; ct < 3; ++ct)
#pragma unroll
    for (int r = 0; r < 16; ++r) {
      const int i = (r & 3) + 8 * (r >> 2) + 4 * hi;
      const int w = ct * 32 + l31 - i;
      if (w >= 0 && w <= 64)
        attn_out[(abase + q0 + i) * WIN + w] = acc[ct][r];
    }

  // ---- PV: ctx[i][d] = sum_k P[i][k] * V[kbase+k][d] ----
  f32x16 accp[2];
#pragma unroll
  for (int dt = 0; dt < 2; ++dt)
#pragma unroll
    for (int r = 0; r < 16; ++r) accp[dt][r] = 0.f;
  __builtin_amdgcn_s_setprio(1);
#pragma unroll
  for (int ks = 0; ks < 6; ++ks) {
    const bf16x8 pa = *(const bf16x8*)&Pl[wv][l31][ks * 16 + hi * 8];
#pragma unroll
    for (int dt = 0; dt < 2; ++dt)
      accp[dt] = __builtin_amdgcn_mfma_f32_32x32x16_bf16(pa, bvf[dt][ks], accp[dt], 0, 0, 0);
  }
  __builtin_amdgcn_s_setprio(0);

  const int b = bh >> 3, h = bh & 7;
  {
    asm volatile("s_waitcnt lgkmcnt(0)" ::: "memory");   // pa reads drained (WAR)
    unsigned short (*ctw)[72] = (unsigned short(*)[72])((unsigned char*)&Pl[wv][0][0]);
#pragma unroll
    for (int dt = 0; dt < 2; ++dt)
#pragma unroll
      for (int r = 0; r < 16; ++r) {
        const int i = (r & 3) + 8 * (r >> 2) + 4 * hi;
        ctw[i][dt * 32 + l31] = f2bf(accp[dt][r]);
      }
    asm volatile("s_waitcnt lgkmcnt(0)" ::: "memory");   // writes visible (RAW)
    unsigned short* cp = &ctxb[((size_t)(b * SEQ + q0)) * DM + h * HD];
#pragma unroll
    for (int it = 0; it < 4; ++it) {
      const int idx = it * 64 + lane;    // 0..255: tok = idx>>3, part = idx&7
      const int tok = idx >> 3, part = idx & 7;
      *(uint4*)&cp[(size_t)tok * DM + part * 8] = *(const uint4*)&ctw[tok][part * 8];
    }
  }
}

extern "C" void kernel_launch(void* const* d_in, const int* in_sizes, int n_in,
                              void* d_out, int out_size, void* d_ws, size_t ws_size,
                              hipStream_t stream) {
  const float* x  = (const float*)d_in[0];
  const float* Wq = (const float*)d_in[1];
  const float* Wk = (const float*)d_in[2];
  const float* Wv = (const float*)d_in[3];
  const float* Wo = (const float*)d_in[4];
  const float* bq = (const float*)d_in[5];
  const float* bk = (const float*)d_in[6];
  const float* bv = (const float*)d_in[7];
  const float* bo = (const float*)d_in[8];

  float* out = (float*)d_out;                        // (B, N, 512) f32
  float* attn_out = out + (size_t)8192 * 512;        // (B, H, N, 65) f32

  char* ws = (char*)d_ws;
  unsigned short* xb   = (unsigned short*)ws;                       // 8,388,608 B
  unsigned short* wt   = (unsigned short*)(ws + 8388608);           // 2,097,152 B
  unsigned short* qkv  = (unsigned short*)(ws + 10485760);          // 25,165,824 B
  unsigned short* ctxb = (unsigned short*)(ws + 35651584);          // 8,388,608 B

  prep_kernel<<<dim3(4352), dim3(256), 0, stream>>>(x, xb, Wq, Wk, Wv, Wo, wt);
  gemm_qkv_kernel<<<dim3(512), dim3(256), 0, stream>>>(xb, wt, bq, bk, bv, qkv);
  attn_kernel<<<dim3(32, 16), dim3(256), 0, stream>>>(
      qkv, qkv + 4194304, qkv + 8388608, attn_out, ctxb);
  gemm_o_kernel<<<dim3(512), dim3(256), 0, stream>>>(ctxb, wt + 3 * 262144, bo, out);
}

// Round 18
// 59.661 us; speedup vs baseline: 1.1192x; 1.0116x over previous
//
#include <hip/hip_runtime.h>
#include <hip/hip_bf16.h>
#include <stdint.h>

#define SEQ 4096
#define DM 512
#define NH 8
#define HD 64
#define WIN 65

typedef __attribute__((ext_vector_type(8))) short bf16x8;
typedef __attribute__((ext_vector_type(4))) float f32x4;
typedef __attribute__((ext_vector_type(16))) float f32x16;

#define GLOAD_LDS16(gp, lp)                                                 \
  __builtin_amdgcn_global_load_lds(                                         \
      (const __attribute__((address_space(1))) void*)(gp),                  \
      (__attribute__((address_space(3))) void*)(lp), 16, 0, 0)

__device__ __forceinline__ unsigned short f2bf(float f) {
  unsigned int u = __float_as_uint(f);
  u += 0x7FFFu + ((u >> 16) & 1u);
  return (unsigned short)(u >> 16);
}

// ---- fused prep: convert x (f32->bf16) and transpose+convert all 4 W ----
__global__ __launch_bounds__(256) void prep_kernel(
    const float* __restrict__ x, unsigned short* __restrict__ xb,
    const float* __restrict__ w0, const float* __restrict__ w1,
    const float* __restrict__ w2, const float* __restrict__ w3,
    unsigned short* __restrict__ wt) {
  __shared__ float tl[64][65];
  const int bid = blockIdx.x;
  const int t = threadIdx.x;
  if (bid < 4096) {
    const int i = bid * 256 + t;
    float4 v = ((const float4*)x)[i];
    ushort4 o;
    o.x = f2bf(v.x); o.y = f2bf(v.y); o.z = f2bf(v.z); o.w = f2bf(v.w);
    ((ushort4*)xb)[i] = o;
    return;
  }
  const int wtid = bid - 4096;          // [0,256)
  const int z = wtid >> 6;
  const int rem = wtid & 63;
  const int k0 = (rem >> 3) * 64;
  const int n0 = (rem & 7) * 64;
  const float* W = (z == 0) ? w0 : (z == 1) ? w1 : (z == 2) ? w2 : w3;
  unsigned short* o = wt + (size_t)z * 262144;
#pragma unroll
  for (int i = 0; i < 16; ++i) {
    int idx = t + i * 256;
    int r = idx >> 6, c = idx & 63;
    tl[c][r] = W[(size_t)(k0 + r) * 512 + n0 + c];
  }
  __syncthreads();
#pragma unroll
  for (int i = 0; i < 16; ++i) {
    int idx = t + i * 256;
    int r = idx >> 6, c = idx & 63;
    o[(size_t)(n0 + r) * 512 + k0 + c] = f2bf(tl[r][c]);
  }
}

// ---- z-merged QKV GEMM (unchanged, R14-proven) ----
__global__ __launch_bounds__(256) void gemm_qkv_kernel(
    const unsigned short* __restrict__ A,
    const unsigned short* __restrict__ wt,
    const float* __restrict__ bq, const float* __restrict__ bk, const float* __restrict__ bv,
    unsigned short* __restrict__ qkv) {
  const int bid = blockIdx.x;
  const int bm = bid & 63;
  const int bn = bid >> 6;            // head 0..7
  const int bm0 = bm * 128;
  const int bn0 = bn * 64;

  __shared__ __align__(16) unsigned char sm[40960];
  unsigned short* As0 = (unsigned short*)sm;                 // [128][32]
  unsigned short* As1 = (unsigned short*)(sm + 8192);

  const int t = threadIdx.x;
  const int lane = t & 63;
  const int wv = t >> 6;
  const int l15 = lane & 15, l4 = lane >> 4;

  const unsigned short* ApA = A + (size_t)(bm0 + wv * 32 + (lane >> 2)) * 512 + (lane & 3) * 8;
  const unsigned short* ApB = ApA + (size_t)16 * 512;
  unsigned short* lA0a = &As0[(wv * 2 + 0) * 512];
  unsigned short* lA0b = &As0[(wv * 2 + 1) * 512];
  unsigned short* lA1a = &As1[(wv * 2 + 0) * 512];
  unsigned short* lA1b = &As1[(wv * 2 + 1) * 512];

  const unsigned short* Bp[3];
  unsigned short *lB0[3], *lB1[3];
  unsigned short *Bz0[3], *Bz1[3];
#pragma unroll
  for (int z = 0; z < 3; ++z) {
    Bp[z] = wt + (size_t)z * 262144 + (size_t)(bn0 + wv * 16 + (lane >> 2)) * 512 + (lane & 3) * 8;
    Bz0[z] = (unsigned short*)(sm + 16384 + z * 8192);          // [64][32]
    Bz1[z] = (unsigned short*)(sm + 16384 + z * 8192 + 4096);   // [64][32]
    lB0[z] = Bz0[z] + wv * 512;
    lB1[z] = Bz1[z] + wv * 512;
  }

  f32x4 acc[3][2][4];
#pragma unroll
  for (int z = 0; z < 3; ++z)
#pragma unroll
    for (int mi = 0; mi < 2; ++mi)
#pragma unroll
      for (int ni = 0; ni < 4; ++ni) acc[z][mi][ni] = (f32x4){0.f, 0.f, 0.f, 0.f};

  for (int kt = 0; kt < 512; kt += 64) {
    __syncthreads();
    GLOAD_LDS16(ApA + kt, lA0a);
    GLOAD_LDS16(ApA + kt + 32, lA1a);
    GLOAD_LDS16(ApB + kt, lA0b);
    GLOAD_LDS16(ApB + kt + 32, lA1b);
#pragma unroll
    for (int z = 0; z < 3; ++z) {
      GLOAD_LDS16(Bp[z] + kt, lB0[z]);
      GLOAD_LDS16(Bp[z] + kt + 32, lB1[z]);
    }
    __syncthreads();
    bf16x8 af0[2], af1[2];
#pragma unroll
    for (int mi = 0; mi < 2; ++mi) {
      const int r = wv * 32 + mi * 16 + l15;
      af0[mi] = *(const bf16x8*)&As0[r * 32 + l4 * 8];
      af1[mi] = *(const bf16x8*)&As1[r * 32 + l4 * 8];
    }
#pragma unroll
    for (int z = 0; z < 3; ++z) {
      bf16x8 b0[4], b1[4];
#pragma unroll
      for (int ni = 0; ni < 4; ++ni) {
        const int rb = ni * 16 + l15;
        b0[ni] = *(const bf16x8*)&Bz0[z][rb * 32 + l4 * 8];
        b1[ni] = *(const bf16x8*)&Bz1[z][rb * 32 + l4 * 8];
      }
#pragma unroll
      for (int mi = 0; mi < 2; ++mi)
#pragma unroll
        for (int ni = 0; ni < 4; ++ni) {
          acc[z][mi][ni] = __builtin_amdgcn_mfma_f32_16x16x32_bf16(af0[mi], b0[ni], acc[z][mi][ni], 0, 0, 0);
          acc[z][mi][ni] = __builtin_amdgcn_mfma_f32_16x16x32_bf16(af1[mi], b1[ni], acc[z][mi][ni], 0, 0, 0);
        }
    }
  }

  const int b = bm0 >> 12;
  const int nn0 = bm0 & 4095;
  // q and k together: two LDS tiles, one barrier pair, contiguous 16KB stores
  {
    __syncthreads();
    unsigned short (*ct0)[72] = (unsigned short(*)[72])sm;
    unsigned short (*ct1)[72] = (unsigned short(*)[72])(sm + 18432);
#pragma unroll
    for (int mi = 0; mi < 2; ++mi)
#pragma unroll
      for (int ni = 0; ni < 4; ++ni) {
        const int col = ni * 16 + l15;
        const float bbq = bq[bn0 + col];
        const float bbk = bk[bn0 + col];
#pragma unroll
        for (int j = 0; j < 4; ++j) {
          const int row = wv * 32 + mi * 16 + l4 * 4 + j;
          ct0[row][col] = f2bf((acc[0][mi][ni][j] + bbq) * 0.125f);
          ct1[row][col] = f2bf(acc[1][mi][ni][j] + bbk);
        }
      }
    __syncthreads();
    unsigned short* opq = qkv + ((size_t)(b * NH + bn) * SEQ + nn0) * HD;
    unsigned short* opk = opq + 4194304;
#pragma unroll
    for (int r = 0; r < 4; ++r) {
      const int idx = r * 256 + t;       // 0..1023
      const int tok = idx >> 3, part = idx & 7;
      *(uint4*)&opq[(size_t)tok * HD + part * 8] = *(const uint4*)&ct0[tok][part * 8];
      *(uint4*)&opk[(size_t)tok * HD + part * 8] = *(const uint4*)&ct1[tok][part * 8];
    }
  }
  // v (z=2): transposed (B*H, 64, N) direct stores (coalesced along n)
  {
    unsigned short* op = qkv + (size_t)2 * 4194304;
#pragma unroll
    for (int mi = 0; mi < 2; ++mi)
#pragma unroll
      for (int ni = 0; ni < 4; ++ni) {
        const int dd = ni * 16 + l15;
        const float bb = bv[bn0 + dd];
        ushort4 o4;
        o4.x = f2bf(acc[2][mi][ni][0] + bb);
        o4.y = f2bf(acc[2][mi][ni][1] + bb);
        o4.z = f2bf(acc[2][mi][ni][2] + bb);
        o4.w = f2bf(acc[2][mi][ni][3] + bb);
        const int gm0 = bm0 + wv * 32 + mi * 16 + l4 * 4;
        const int nn = gm0 & 4095;
        *(ushort4*)&op[((size_t)(b * NH + bn) * HD + dd) * SEQ + nn] = o4;
      }
  }
}

// ---- Wo GEMM: BM=64, BN=64, grid 1024 = 4 blocks/CU (occupancy lever),
// LDS 17.4KB, f32 out via LDS-staged coalesced epilogue ----
__global__ __launch_bounds__(256) void gemm_o_kernel(
    const unsigned short* __restrict__ A,
    const unsigned short* __restrict__ wt,
    const float* __restrict__ bias,
    float* __restrict__ outp) {
  const int bid = blockIdx.x;
  const int bm = bid & 127;
  const int bn = bid >> 7;            // 0..7
  const int bm0 = bm * 64;
  const int bn0 = bn * 64;
  const unsigned short* W = wt;

  __shared__ __align__(16) unsigned char sm[17408];
  unsigned short* As0 = (unsigned short*)sm;                    // [64][32]
  unsigned short* As1 = (unsigned short*)(sm + 4096);
  unsigned short* Bs0 = (unsigned short*)(sm + 8192);           // [64][32]
  unsigned short* Bs1 = (unsigned short*)(sm + 12288);

  const int t = threadIdx.x;
  const int lane = t & 63;
  const int wv = t >> 6;
  const int wr = wv >> 1, wc = wv & 1;
  const int l15 = lane & 15, l4 = lane >> 4;

  const unsigned short* ApA = A + (size_t)(bm0 + wv * 16 + (lane >> 2)) * 512 + (lane & 3) * 8;
  unsigned short* lA0a = &As0[wv * 512];
  unsigned short* lA1a = &As1[wv * 512];
  const unsigned short* BpA = W + (size_t)(bn0 + wv * 16 + (lane >> 2)) * 512 + (lane & 3) * 8;
  unsigned short* lB0a = &Bs0[wv * 512];
  unsigned short* lB1a = &Bs1[wv * 512];

  f32x4 acc[2][2];
#pragma unroll
  for (int i = 0; i < 2; ++i)
#pragma unroll
    for (int j = 0; j < 2; ++j) acc[i][j] = (f32x4){0.f, 0.f, 0.f, 0.f};

  for (int kt = 0; kt < 512; kt += 64) {
    __syncthreads();
    GLOAD_LDS16(ApA + kt, lA0a);
    GLOAD_LDS16(ApA + kt + 32, lA1a);
    GLOAD_LDS16(BpA + kt, lB0a);
    GLOAD_LDS16(BpA + kt + 32, lB1a);
    __syncthreads();
    bf16x8 af0[2], af1[2], bf0[2], bf1[2];
#pragma unroll
    for (int mi = 0; mi < 2; ++mi) {
      const int r = wr * 32 + mi * 16 + l15;
      af0[mi] = *(const bf16x8*)&As0[r * 32 + l4 * 8];
      af1[mi] = *(const bf16x8*)&As1[r * 32 + l4 * 8];
    }
#pragma unroll
    for (int ni = 0; ni < 2; ++ni) {
      const int r = wc * 32 + ni * 16 + l15;
      bf0[ni] = *(const bf16x8*)&Bs0[r * 32 + l4 * 8];
      bf1[ni] = *(const bf16x8*)&Bs1[r * 32 + l4 * 8];
    }
#pragma unroll
    for (int mi = 0; mi < 2; ++mi)
#pragma unroll
      for (int ni = 0; ni < 2; ++ni) {
        acc[mi][ni] = __builtin_amdgcn_mfma_f32_16x16x32_bf16(af0[mi], bf0[ni], acc[mi][ni], 0, 0, 0);
        acc[mi][ni] = __builtin_amdgcn_mfma_f32_16x16x32_bf16(af1[mi], bf1[ni], acc[mi][ni], 0, 0, 0);
      }
  }

  __syncthreads();
  float (*cf)[68] = (float(*)[68])sm;    // [64][68] f32 = 17408 B
#pragma unroll
  for (int mi = 0; mi < 2; ++mi)
#pragma unroll
    for (int ni = 0; ni < 2; ++ni) {
      const int col = wc * 32 + ni * 16 + l15;
      const float bb = bias[bn0 + col];
#pragma unroll
      for (int j = 0; j < 4; ++j)
        cf[wr * 32 + mi * 16 + l4 * 4 + j][col] = acc[mi][ni][j] + bb;
    }
  __syncthreads();
  float* op = outp + (size_t)bm0 * 512 + bn0;
#pragma unroll
  for (int r = 0; r < 4; ++r) {
    const int idx = r * 256 + t;           // 0..1023
    const int tok = idx >> 4;              // 0..63
    const int part = idx & 15;
    *(float4*)&op[(size_t)tok * 512 + part * 4] = *(const float4*)&cf[tok][part * 4];
  }
}

// ---- MFMA local attention, 32x32x16 (R17-proven: V-defer + setprio) ----
__global__ __launch_bounds__(256) void attn_kernel(
    const unsigned short* __restrict__ qb, const unsigned short* __restrict__ kb,
    const unsigned short* __restrict__ vt,
    float* __restrict__ attn_out, unsigned short* __restrict__ ctxb) {
  __shared__ unsigned short Pl[4][32][104];   // bf16 P, rows=query, cols=key 0..95
  const int t = threadIdx.x;
  const int lane = t & 63;
  const int wv = t >> 6;              // 0..3
  const int l31 = lane & 31;
  const int hi = lane >> 5;
  const int bh = blockIdx.y;
  const int q0 = blockIdx.x * 128 + wv * 32;
  const int kbase = q0 - 32;
  const size_t base = (size_t)bh * SEQ * HD;

  bf16x8 aq[4];
#pragma unroll
  for (int kc = 0; kc < 4; ++kc)
    aq[kc] = *(const bf16x8*)&qb[base + (size_t)(q0 + l31) * HD + kc * 16 + hi * 8];

  f32x16 acc[3];
#pragma unroll
  for (int ct = 0; ct < 3; ++ct) {
#pragma unroll
    for (int r = 0; r < 16; ++r) acc[ct][r] = 0.f;
    const int krow = kbase + ct * 32 + l31;
    bf16x8 bk[4];
    if (krow >= 0 && krow < SEQ) {
#pragma unroll
      for (int kc = 0; kc < 4; ++kc)
        bk[kc] = *(const bf16x8*)&kb[base + (size_t)krow * HD + kc * 16 + hi * 8];
    } else {
#pragma unroll
      for (int kc = 0; kc < 4; ++kc) bk[kc] = (bf16x8){0, 0, 0, 0, 0, 0, 0, 0};
    }
    __builtin_amdgcn_s_setprio(1);
#pragma unroll
    for (int kc = 0; kc < 4; ++kc)
      acc[ct] = __builtin_amdgcn_mfma_f32_32x32x16_bf16(aq[kc], bk[kc], acc[ct], 0, 0, 0);
    __builtin_amdgcn_s_setprio(0);
  }

#pragma unroll
  for (int ct = 0; ct < 3; ++ct)
#pragma unroll
    for (int r = 0; r < 16; ++r) {
      const int i = (r & 3) + 8 * (r >> 2) + 4 * hi;
      const int w = ct * 32 + l31 - i;
      if (!(w >= 0 && w <= 64)) acc[ct][r] = -3.0e38f;
    }
  float m16[16], inv16[16];
#pragma unroll
  for (int r = 0; r < 16; ++r) {
    float m = fmaxf(fmaxf(acc[0][r], acc[1][r]), acc[2][r]);
#pragma unroll
    for (int o = 16; o; o >>= 1) m = fmaxf(m, __shfl_xor(m, o));
    m16[r] = m;
  }
#pragma unroll
  for (int ct = 0; ct < 3; ++ct)
#pragma unroll
    for (int r = 0; r < 16; ++r)
      acc[ct][r] = (acc[ct][r] > -1.0e38f) ? __expf(acc[ct][r] - m16[r]) : 0.f;
#pragma unroll
  for (int r = 0; r < 16; ++r) {
    float s = acc[0][r] + acc[1][r] + acc[2][r];
#pragma unroll
    for (int o = 16; o; o >>= 1) s += __shfl_xor(s, o);
    inv16[r] = 1.f / s;
  }
#pragma unroll
  for (int ct = 0; ct < 3; ++ct)
#pragma unroll
    for (int r = 0; r < 16; ++r)
      acc[ct][r] *= inv16[r];

  // ---- P -> bf16 LDS ----
#pragma unroll
  for (int ct = 0; ct < 3; ++ct)
#pragma unroll
    for (int r = 0; r < 16; ++r) {
      const int i = (r & 3) + 8 * (r >> 2) + 4 * hi;
      Pl[wv][i][ct * 32 + l31] = f2bf(acc[ct][r]);
    }

  // ---- V loads (deferred: issued here, covered by attn_out store burst) ----
  bf16x8 bvf[2][6];
#pragma unroll
  for (int ks = 0; ks < 6; ++ks) {
    const int key0 = kbase + ks * 16 + hi * 8;
    const bool inr = (key0 >= 0 && key0 < SEQ);
    const int ksafe = inr ? key0 : 0;
#pragma unroll
    for (int dt = 0; dt < 2; ++dt) {
      bf16x8 v = *(const bf16x8*)&vt[((size_t)bh * HD + dt * 32 + l31) * SEQ + ksafe];
      bvf[dt][ks] = inr ? v : (bf16x8){0, 0, 0, 0, 0, 0, 0, 0};
    }
  }

  // ---- attn_out stores from registers ----
  const size_t abase = (size_t)bh * SEQ;
#pragma unroll
  for (int ct = 0; ct < 3; ++ct)
#pragma unroll
    for (int r = 0; r < 16; ++r) {
      const int i = (r & 3) + 8 * (r >> 2) + 4 * hi;
      const int w = ct * 32 + l31 - i;
      if (w >= 0 && w <= 64)
        attn_out[(abase + q0 + i) * WIN + w] = acc[ct][r];
    }

  // ---- PV: ctx[i][d] = sum_k P[i][k] * V[kbase+k][d] ----
  f32x16 accp[2];
#pragma unroll
  for (int dt = 0; dt < 2; ++dt)
#pragma unroll
    for (int r = 0; r < 16; ++r) accp[dt][r] = 0.f;
  __builtin_amdgcn_s_setprio(1);
#pragma unroll
  for (int ks = 0; ks < 6; ++ks) {
    const bf16x8 pa = *(const bf16x8*)&Pl[wv][l31][ks * 16 + hi * 8];
#pragma unroll
    for (int dt = 0; dt < 2; ++dt)
      accp[dt] = __builtin_amdgcn_mfma_f32_32x32x16_bf16(pa, bvf[dt][ks], accp[dt], 0, 0, 0);
  }
  __builtin_amdgcn_s_setprio(0);

  const int b = bh >> 3, h = bh & 7;
  {
    asm volatile("s_waitcnt lgkmcnt(0)" ::: "memory");   // pa reads drained (WAR)
    unsigned short (*ctw)[72] = (unsigned short(*)[72])((unsigned char*)&Pl[wv][0][0]);
#pragma unroll
    for (int dt = 0; dt < 2; ++dt)
#pragma unroll
      for (int r = 0; r < 16; ++r) {
        const int i = (r & 3) + 8 * (r >> 2) + 4 * hi;
        ctw[i][dt * 32 + l31] = f2bf(accp[dt][r]);
      }
    asm volatile("s_waitcnt lgkmcnt(0)" ::: "memory");   // writes visible (RAW)
    unsigned short* cp = &ctxb[((size_t)(b * SEQ + q0)) * DM + h * HD];
#pragma unroll
    for (int it = 0; it < 4; ++it) {
      const int idx = it * 64 + lane;    // 0..255: tok = idx>>3, part = idx&7
      const int tok = idx >> 3, part = idx & 7;
      *(uint4*)&cp[(size_t)tok * DM + part * 8] = *(const uint4*)&ctw[tok][part * 8];
    }
  }
}

extern "C" void kernel_launch(void* const* d_in, const int* in_sizes, int n_in,
                              void* d_out, int out_size, void* d_ws, size_t ws_size,
                              hipStream_t stream) {
  const float* x  = (const float*)d_in[0];
  const float* Wq = (const float*)d_in[1];
  const float* Wk = (const float*)d_in[2];
  const float* Wv = (const float*)d_in[3];
  const float* Wo = (const float*)d_in[4];
  const float* bq = (const float*)d_in[5];
  const float* bk = (const float*)d_in[6];
  const float* bv = (const float*)d_in[7];
  const float* bo = (const float*)d_in[8];

  float* out = (float*)d_out;                        // (B, N, 512) f32
  float* attn_out = out + (size_t)8192 * 512;        // (B, H, N, 65) f32

  char* ws = (char*)d_ws;
  unsigned short* xb   = (unsigned short*)ws;                       // 8,388,608 B
  unsigned short* wt   = (unsigned short*)(ws + 8388608);           // 2,097,152 B
  unsigned short* qkv  = (unsigned short*)(ws + 10485760);          // 25,165,824 B
  unsigned short* ctxb = (unsigned short*)(ws + 35651584);          // 8,388,608 B

  prep_kernel<<<dim3(4352), dim3(256), 0, stream>>>(x, xb, Wq, Wk, Wv, Wo, wt);
  gemm_qkv_kernel<<<dim3(512), dim3(256), 0, stream>>>(xb, wt, bq, bk, bv, qkv);
  attn_kernel<<<dim3(32, 16), dim3(256), 0, stream>>>(
      qkv, qkv + 4194304, qkv + 8388608, attn_out, ctxb);
  gemm_o_kernel<<<dim3(1024), dim3(256), 0, stream>>>(ctxb, wt + 3 * 262144, bo, out);
}